// Round 8
// baseline (630.519 us; speedup 1.0000x reference)
//
#include <hip/hip_runtime.h>
#include <cstdint>

constexpr int B    = 256;
constexpr int S    = 33;
constexpr int D    = 42;
constexpr int H    = 128;
constexpr int HFF  = 256;
constexpr int T    = 20;
constexpr int NSTEP = S - 1;   // 32
constexpr int DP   = D / 2;    // 21 f16 d-pairs
constexpr int ADW  = 8192;     // dwords per (s,b) A-slice (e5m2, 32 KB)
constexpr int CH   = 8;        // steps per chunk (A chunk = 64 MiB, double-buffered)
constexpr int NCH  = NSTEP / CH;  // 4 chunks
#define BN_SCALE 0.9999950000374997f

typedef _Float16 h2v __attribute__((ext_vector_type(2)));
typedef _Float16 f16x8 __attribute__((ext_vector_type(8)));
typedef float    f32x4 __attribute__((ext_vector_type(4)));
union UH2 { uint32_t u; h2v h; };

__device__ __forceinline__ float fdot2u(uint32_t a, uint32_t b, float c) {
    UH2 x, y; x.u = a; y.u = b;
    return __builtin_amdgcn_fdot2(x.h, y.h, c, false);
}
__device__ __forceinline__ uint32_t packh2(float a, float b) {
    UH2 u; u.h = h2v{(_Float16)a, (_Float16)b}; return u.u;
}
__device__ __forceinline__ float gelu_exact(float x) {
    return 0.5f * x * (1.0f + erff(x * 0.70710678118654752f));
}
// fast gelu for the hot scan (err ~3e-4, far under the 1e-2 threshold)
__device__ __forceinline__ float gelu_fast(float x) {
    float inner = x * (1.0f + 0.044715f * x * x);
    float E = __expf(1.5957691216f * inner);
    return x * E * __frcp_rn(E + 1.0f);
}
// A-staging swizzle (uint4 index): column ^= (row>>4)<<1 so that L3's
// intra-wave (h = t>>2, g = t&3) reads land 2-way max on LDS banks.
__device__ __forceinline__ int aswz(int idx) {
    return (idx & ~31) | ((idx & 31) ^ (((idx >> 9) & 3) << 1));
}

// ---------------------------------------------------------------------------
// Pack (one-time):
//  wcol[r*512 + t]: f16-pair weight-column slices for the 512-thread scan.
//  wp[m][64] f16 (32 dwords/row): A-operand for the MFMA aphase.
//    m = byte index in an A-slice: e = 4*(m>>9) + (m&3); h = (m>>2)&127;
//    wp[m][d] = w3[e][h*D + d] for d<42, else 0.  Positional (identity-d)
//    packing of BOTH operands makes the intra-fragment k order cancel.
// ---------------------------------------------------------------------------
__global__ void pack_kernel(const float* __restrict__ w0, const float* __restrict__ w1,
                            const float* __restrict__ w2, const float* __restrict__ w3,
                            uint32_t* __restrict__ wcol, uint32_t* __restrict__ wp) {
    int idx = blockIdx.x * 256 + threadIdx.x;
    if (idx < 160 * 512) {
        int r = idx >> 9, t = idx & 511;
        int j = t >> 1, half = t & 1;
        float a, bb;
        if (r < 32)      { int ip = half * 32 + r;      a = w0[(2*ip)*HFF + j]; bb = w0[(2*ip+1)*HFF + j]; }
        else if (r < 96) { int ip = half * 64 + (r-32); a = w1[(2*ip)*HFF + j]; bb = w1[(2*ip+1)*HFF + j]; }
        else             { int ip = half * 64 + (r-96); a = w2[(2*ip)*HFF + j]; bb = w2[(2*ip+1)*HFF + j]; }
        wcol[idx] = packh2(a, bb);
    }
    if (idx < 32768 * 32) {
        int m = idx >> 5, dd = (idx & 31) * 2;
        int e = 4 * (m >> 9) + (m & 3);
        int h = (m >> 2) & 127;
        const float* row = w3 + (size_t)e * (H * D) + h * D;
        float a = (dd     < D) ? row[dd]     : 0.f;
        float b = (dd + 1 < D) ? row[dd + 1] : 0.f;
        wp[idx] = packh2(a, b);
    }
}

// ---------------------------------------------------------------------------
// Prep: encoder z0, dxdt padded f16 rows (64 wide, zeros d>=42), bd3g, dt.
// ---------------------------------------------------------------------------
__global__ void prep_kernel(const float* __restrict__ path, const float* __restrict__ ts,
                            const float* __restrict__ ew1, const float* __restrict__ eb1,
                            const float* __restrict__ eg1, const float* __restrict__ ebe1,
                            const float* __restrict__ ew2, const float* __restrict__ eb2,
                            const float* __restrict__ eg2, const float* __restrict__ ebe2,
                            const float* __restrict__ b3,
                            float* __restrict__ zbuf, uint32_t* __restrict__ dxp,
                            float* __restrict__ bd3g, float* __restrict__ dtb) {
    __shared__ float x0[D], hb[H], dxs[NSTEP][D];
    int b = blockIdx.x, tid = threadIdx.x;
    if (tid < D) x0[tid] = path[b * S * D + tid];
    __syncthreads();
    {
        float acc = eb1[tid];
        for (int d = 0; d < D; ++d) acc += x0[d] * ew1[d * H + tid];
        hb[tid] = gelu_exact(acc * (eg1[tid] * BN_SCALE) + ebe1[tid]);
    }
    __syncthreads();
    {
        float acc = eb2[tid];
        for (int i = 0; i < H; ++i) acc += hb[i] * ew2[i * H + tid];
        zbuf[b * H + tid] = acc * (eg2[tid] * BN_SCALE) + ebe2[tid];
    }
    for (int idx = tid; idx < NSTEP * 32; idx += 128) {
        int s = idx >> 5, j2 = idx & 31;
        uint32_t val = 0;
        if (j2 < DP) {
            float dtv = ts[s + 1] - ts[s];
            int base = b * S * D + s * D + 2 * j2;
            float v0 = (path[base + D] - path[base]) / dtv;
            float v1 = (path[base + D + 1] - path[base + 1]) / dtv;
            dxs[s][2 * j2] = v0; dxs[s][2 * j2 + 1] = v1;
            val = packh2(v0, v1);
        }
        dxp[((size_t)(s * B + b)) * 32 + j2] = val;
    }
    __syncthreads();
    for (int s = 0; s < NSTEP; ++s) {
        float a = 0.f;
        for (int d = 0; d < D; ++d) a += b3[tid * D + d] * dxs[s][d];
        bd3g[(size_t)(s * B + b) * H + tid] = a;
    }
    if (b == 0 && tid < NSTEP) dtb[tid] = ts[tid + 1] - ts[tid];
}

// ---------------------------------------------------------------------------
// Standalone MFMA A-phase (chunk 0 only — nothing to overlap with).
// A[q][m] = sum_d wp[m][d] * dx[q][d]; 2048 slices/chunk at CH=8.
// grid = 64 m-groups x 16 slice-groups = 1024 blocks, 256 thr = 4 waves.
// C layout (HW-verified m89): col=lane&15 = slice, rows (lane>>4)*4+reg =
// 4 consecutive m -> 4 e5m2 bytes pack to one dword store.
// ---------------------------------------------------------------------------
__global__ void __launch_bounds__(256) amm_kernel(
    const uint32_t* __restrict__ wp, const uint32_t* __restrict__ dxp,
    uint32_t* __restrict__ Ach, int s0) {
    int t = threadIdx.x;
    int l = t & 63, wid = t >> 6;
    int mg = (blockIdx.x & 63) * 4 + wid;        // 0..255
    int sg = blockIdx.x >> 6;                    // 0..15
    int lr = l & 15, lk = l >> 4;
    const char* wpB = (const char*)wp;
    const char* dxB = (const char*)dxp + (size_t)s0 * B * 128;
    char* asB = (char*)Ach;
    f16x8 af0[8], af1[8];
#pragma unroll
    for (int mi = 0; mi < 8; ++mi) {
        const f16x8* p = (const f16x8*)(wpB + ((size_t)(mg * 8 + mi) * 16 + lr) * 128 + lk * 16);
        af0[mi] = p[0]; af1[mi] = p[4];          // d 0..31, d 32..63
    }
#pragma unroll
    for (int si = 0; si < 8; ++si) {
        int q = sg * 128 + si * 16 + lr;         // chunk-local slice
        const f16x8* bp = (const f16x8*)(dxB + (size_t)q * 128 + lk * 16);
        f16x8 b0 = bp[0], b1 = bp[4];
        char* outB = asB + (size_t)q * 32768 + (mg * 128 + lk * 4);
#pragma unroll
        for (int mi = 0; mi < 8; ++mi) {
            f32x4 acc = {0.f, 0.f, 0.f, 0.f};
            acc = __builtin_amdgcn_mfma_f32_16x16x32_f16(af0[mi], b0, acc, 0, 0, 0);
            acc = __builtin_amdgcn_mfma_f32_16x16x32_f16(af1[mi], b1, acc, 0, 0, 0);
            uint32_t P0 = packh2(acc[0], acc[1]) + 0x00800080u;
            uint32_t P1 = packh2(acc[2], acc[3]) + 0x00800080u;
            uint32_t Q = __builtin_amdgcn_perm(P1, P0, 0x07050301u);
            *(uint32_t*)(outB + mi * 16) = Q;
        }
    }
}

// ---------------------------------------------------------------------------
// FUSED: blocks [0,B) = scan for chunk s0_scan (reads AchR); blocks
// [B, B+512) = MFMA amm for the NEXT chunk (s0_amm -> AchW).  Overlap
// rationale vs round-6's failure: that aphase role was VALU-heavy fdot2,
// competing head-on with the scan's VALU chain (scan 2x slower).  The amm
// role is MFMA-pipe + VMEM stores + zero LDS + trivial VALU — the pipes
// the scan leaves idle (m114: MFMA and VALU waves co-schedule ~max).
// LDS = scan's 67.6 KB only -> 2 blocks/CU -> each CU: 1 scan + 1 amm.
// Scan body = round-4/7 structure verbatim (proven, VGPR 120, no spill).
// ---------------------------------------------------------------------------
__global__ void __launch_bounds__(512, 1)
__attribute__((amdgpu_waves_per_eu(2, 8)))
fused_kernel(
    const uint32_t* __restrict__ wcol, const uint32_t* __restrict__ AchR,
    uint32_t* __restrict__ AchW,
    const uint32_t* __restrict__ wp, const uint32_t* __restrict__ dxp,
    const float* __restrict__ vb0, const float* __restrict__ vg0, const float* __restrict__ vbe0,
    const float* __restrict__ vb1, const float* __restrict__ vg1, const float* __restrict__ vbe1,
    const float* __restrict__ vb2, const float* __restrict__ vg2, const float* __restrict__ vbe2,
    const float* __restrict__ bd3g, const float* __restrict__ dtb,
    float* __restrict__ zbuf, int s0_scan, int s0_amm) {
    __shared__ __align__(16) uint32_t ABUF[2][ADW];            // 64 KB
    __shared__ __align__(16) uint32_t zzPd[72];                // half*36 + r
    __shared__ __align__(16) uint32_t yA[136], yB[136], yC[136]; // half*68 + r
    int t = threadIdx.x;

    if (blockIdx.x >= B) {
        // ---------------- amm role: 8 waves, no LDS ----------------
        int rid = blockIdx.x - B;                  // 0..511
        int wid = t >> 6, l = t & 63;
        int gw = rid * 8 + wid;                    // 0..4095
        int mg = gw & 255, sg = gw >> 8;           // 256 mg x 16 sg
        int lr = l & 15, lk = l >> 4;
        const char* wpB = (const char*)wp;
        const char* dxB = (const char*)dxp + (size_t)s0_amm * B * 128;
        char* asB = (char*)AchW;
        f16x8 af0[8], af1[8];
#pragma unroll
        for (int mi = 0; mi < 8; ++mi) {
            const f16x8* p = (const f16x8*)(wpB + ((size_t)(mg * 8 + mi) * 16 + lr) * 128 + lk * 16);
            af0[mi] = p[0]; af1[mi] = p[4];
        }
#pragma unroll
        for (int si = 0; si < 8; ++si) {
            int q = sg * 128 + si * 16 + lr;
            const f16x8* bp = (const f16x8*)(dxB + (size_t)q * 128 + lk * 16);
            f16x8 b0 = bp[0], b1 = bp[4];
            char* outB = asB + (size_t)q * 32768 + (mg * 128 + lk * 4);
#pragma unroll
            for (int mi = 0; mi < 8; ++mi) {
                f32x4 acc = {0.f, 0.f, 0.f, 0.f};
                acc = __builtin_amdgcn_mfma_f32_16x16x32_f16(af0[mi], b0, acc, 0, 0, 0);
                acc = __builtin_amdgcn_mfma_f32_16x16x32_f16(af1[mi], b1, acc, 0, 0, 0);
                uint32_t P0 = packh2(acc[0], acc[1]) + 0x00800080u;
                uint32_t P1 = packh2(acc[2], acc[3]) + 0x00800080u;
                uint32_t Q = __builtin_amdgcn_perm(P1, P0, 0x07050301u);
                *(uint32_t*)(outB + mi * 16) = Q;
            }
        }
        return;
    }

    // ---------------- scan role: 512 threads, 1 sample ----------------
    __builtin_amdgcn_s_setprio(1);
    int b = blockIdx.x;
    int j = t >> 1, half = t & 1;                     // MLP role
    int h = t >> 2, g = t & 3;                        // L3/state role
    int hswz = h ^ (g << 3);                          // swizzled A column
    uint32_t w0h[32], w1h[64], w2h[64];
#pragma unroll
    for (int r = 0; r < 32; ++r) w0h[r] = wcol[r * 512 + t];
#pragma unroll
    for (int r = 0; r < 64; ++r) w1h[r] = wcol[(32 + r) * 512 + t];
#pragma unroll
    for (int r = 0; r < 64; ++r) w2h[r] = wcol[(96 + r) * 512 + t];
    float c0s = vg0[j] * BN_SCALE, c0o = vb0[j] * c0s + vbe0[j];
    float c1s = vg1[j] * BN_SCALE, c1o = vb1[j] * c1s + vbe1[j];
    float c2s = vg2[j] * BN_SCALE, c2o = vb2[j] * c2s + vbe2[j];
    float zf = zbuf[b * H + h];
    {
        const uint4* Ag = (const uint4*)(AchR + (size_t)b * ADW);
        uint4 a0 = Ag[t], a1 = Ag[512 + t], a2 = Ag[1024 + t], a3 = Ag[1536 + t];
        uint4* Ad = (uint4*)ABUF[0];
        Ad[aswz(t)] = a0; Ad[aswz(512 + t)] = a1;
        Ad[aswz(1024 + t)] = a2; Ad[aswz(1536 + t)] = a3;
    }
    {
        float zhi = __shfl_down(zf, 4, 64);
        if ((t & 7) == 0) {
            int ip = t >> 3;
            zzPd[(ip >> 5) * 36 + (ip & 31)] = packh2(zf, zhi);
        }
    }
    __syncthreads();

    for (int sl = 0; sl < CH; ++sl) {
        int s = s0_scan + sl;
        float hstep = dtb[s];
        float bd3 = bd3g[(size_t)(s * B + b) * H + h];
        uint4 pf0, pf1, pf2, pf3;
        {
            int sn = (sl + 1 < CH) ? sl + 1 : sl;
            const uint4* Ag = (const uint4*)(AchR + (size_t)(sn * B + b) * ADW);
            pf0 = Ag[t]; pf1 = Ag[512 + t]; pf2 = Ag[1024 + t]; pf3 = Ag[1536 + t];
        }
        const uint32_t* AL = ABUF[sl & 1];
        float ksum = 0.f, kcur = 0.f;
        for (int r = 0; r < 4; ++r) {
            // ---- L0 ----
            {
                float pa = 0.f, pb = 0.f, pc = 0.f, pd = 0.f;
                const uint4* zq = (const uint4*)(zzPd + half * 36);
#pragma unroll
                for (int u4 = 0; u4 < 8; ++u4) {
                    uint4 zv = zq[u4];
                    pa = fdot2u(w0h[4*u4+0], zv.x, pa); pb = fdot2u(w0h[4*u4+1], zv.y, pb);
                    pc = fdot2u(w0h[4*u4+2], zv.z, pc); pd = fdot2u(w0h[4*u4+3], zv.w, pd);
                }
                float p = (pa + pb) + (pc + pd);
                p += __shfl_xor(p, 1, 64);
                float v = gelu_fast(p * c0s + c0o);
                float vhi = __shfl_down(v, 2, 64);
                if ((t & 3) == 0) {
                    int ip = t >> 2;
                    yA[(ip >> 6) * 68 + (ip & 63)] = packh2(v, vhi);
                }
            }
            __syncthreads();
            // ---- L1 ----
            {
                float pa = 0.f, pb = 0.f, pc = 0.f, pd = 0.f;
                const uint4* yq = (const uint4*)(yA + half * 68);
#pragma unroll
                for (int u4 = 0; u4 < 16; ++u4) {
                    uint4 yv = yq[u4];
                    pa = fdot2u(w1h[4*u4+0], yv.x, pa); pb = fdot2u(w1h[4*u4+1], yv.y, pb);
                    pc = fdot2u(w1h[4*u4+2], yv.z, pc); pd = fdot2u(w1h[4*u4+3], yv.w, pd);
                }
                float p = (pa + pb) + (pc + pd);
                p += __shfl_xor(p, 1, 64);
                float v = gelu_fast(p * c1s + c1o);
                float vhi = __shfl_down(v, 2, 64);
                if ((t & 3) == 0) {
                    int ip = t >> 2;
                    yB[(ip >> 6) * 68 + (ip & 63)] = packh2(v, vhi);
                }
            }
            __syncthreads();
            // ---- L2 ----
            {
                float pa = 0.f, pb = 0.f, pc = 0.f, pd = 0.f;
                const uint4* yq = (const uint4*)(yB + half * 68);
#pragma unroll
                for (int u4 = 0; u4 < 16; ++u4) {
                    uint4 yv = yq[u4];
                    pa = fdot2u(w2h[4*u4+0], yv.x, pa); pb = fdot2u(w2h[4*u4+1], yv.y, pb);
                    pc = fdot2u(w2h[4*u4+2], yv.z, pc); pd = fdot2u(w2h[4*u4+3], yv.w, pd);
                }
                float p = (pa + pb) + (pc + pd);
                p += __shfl_xor(p, 1, 64);
                float v = gelu_fast(p * c2s + c2o);
                float vhi = __shfl_down(v, 2, 64);
                if ((t & 3) == 0) {
                    int ip = t >> 2;
                    yC[(ip >> 6) * 68 + (ip & 63)] = packh2(v, vhi);
                }
            }
            __syncthreads();
            // ---- L3 + state (fused) ----
            {
                float pA = 0.f, pB = 0.f, pC = 0.f, pD = 0.f;
                int ybase = (g >> 1) * 68 + (g & 1) * 32;
                const uint4* yq = (const uint4*)(yC + ybase);
#pragma unroll
                for (int kk = 0; kk < 8; ++kk) {
                    uint4 yv = yq[kk];
                    int k0 = g * 16 + 2 * kk;
                    uint32_t Qa = AL[k0 * 128 + hswz];
                    uint32_t Qb = AL[(k0 + 1) * 128 + hswz];
                    pA = fdot2u(__builtin_amdgcn_perm(0u, Qa, 0x010C000Cu), yv.x, pA);
                    pB = fdot2u(__builtin_amdgcn_perm(0u, Qa, 0x030C020Cu), yv.y, pB);
                    pC = fdot2u(__builtin_amdgcn_perm(0u, Qb, 0x010C000Cu), yv.z, pC);
                    pD = fdot2u(__builtin_amdgcn_perm(0u, Qb, 0x030C020Cu), yv.w, pD);
                }
                float ptot = (pA + pB) + (pC + pD);
                ptot += __shfl_xor(ptot, 1, 64);
                ptot += __shfl_xor(ptot, 2, 64);
                kcur = bd3 + ptot;
                float wsm = (r == 1 || r == 2) ? 2.f : 1.f;
                ksum += wsm * kcur;
                float zz;
                if (r < 3) {
                    float cin = (r == 2) ? 1.f : 0.5f;
                    zz = zf + cin * hstep * kcur;
                } else {
                    zf += hstep * (1.f / 6.f) * ksum;
                    zz = zf;
                }
                float zhi = __shfl_down(zz, 4, 64);
                if ((t & 7) == 0) {
                    int ip = t >> 3;
                    zzPd[(ip >> 5) * 36 + (ip & 31)] = packh2(zz, zhi);
                }
            }
            if (r == 3) {
                uint4* Ad = (uint4*)ABUF[(sl + 1) & 1];
                Ad[aswz(t)] = pf0; Ad[aswz(512 + t)] = pf1;
                Ad[aswz(1024 + t)] = pf2; Ad[aswz(1536 + t)] = pf3;
            }
            __syncthreads();
        }
    }
    if ((t & 3) == 0) zbuf[b * H + h] = zf;
}

// ---------------------------------------------------------------------------
// attended = (zT@wv+bv)@wo+bo.  One block per sample, 128 threads.
// ---------------------------------------------------------------------------
__global__ void att_kernel(const float* __restrict__ zbuf,
                           const float* __restrict__ wv, const float* __restrict__ bv,
                           const float* __restrict__ wo, const float* __restrict__ bo,
                           float* __restrict__ att) {
    __shared__ float zl[H], v[H];
    int b = blockIdx.x, tid = threadIdx.x;
    zl[tid] = zbuf[b * H + tid];
    __syncthreads();
    {
        float acc = bv[tid];
#pragma unroll 8
        for (int i = 0; i < H; ++i) acc += zl[i] * wv[i * H + tid];
        v[tid] = acc;
    }
    __syncthreads();
    {
        float acc = bo[tid];
#pragma unroll 8
        for (int i = 0; i < H; ++i) acc += v[i] * wo[i * H + tid];
        att[b * H + tid] = acc;
    }
}

// ---------------------------------------------------------------------------
// Decoder: one single-wave block per (t, b).  grid = T*B = 5120.
// ---------------------------------------------------------------------------
__global__ void __launch_bounds__(64) dec_kernel(
    const float* __restrict__ att,
    const float* __restrict__ dw1, const float* __restrict__ db1,
    const float* __restrict__ dw2, const float* __restrict__ db2,
    const float* __restrict__ dw3, const float* __restrict__ db3,
    float* __restrict__ out) {
    int bid = blockIdx.x;
    int t = bid >> 8, b = bid & 255;
    int tid = threadIdx.x;
    __shared__ float al[H], h1l[64];
    al[tid] = att[b * H + tid];
    al[tid + 64] = att[b * H + tid + 64];
    __syncthreads();
    {
        float acc = db1[t * 64 + tid];
#pragma unroll 8
        for (int i = 0; i < H; ++i) acc += al[i] * dw1[t * H * 64 + i * 64 + tid];
        h1l[tid] = gelu_exact(acc);
    }
    __syncthreads();
    float v = 0.f;
    if (tid < 32) {
        float acc = db2[t * 32 + tid];
#pragma unroll 8
        for (int i = 0; i < 64; ++i) acc += h1l[i] * dw2[t * 64 * 32 + i * 32 + tid];
        v = gelu_exact(acc) * dw3[t * 32 + tid];
    }
#pragma unroll
    for (int off = 16; off >= 1; off >>= 1) v += __shfl_down(v, off, 64);
    if (tid == 0) out[b * T + t] = 1.f / (1.f + expf(-(v + db3[t])));
}

// ---------------------------------------------------------------------------
extern "C" void kernel_launch(void* const* d_in, const int* in_sizes, int n_in,
                              void* d_out, int out_size, void* d_ws, size_t ws_size,
                              hipStream_t stream) {
    const float* path = (const float*)d_in[0];
    const float* ts   = (const float*)d_in[1];
    const float* ew1  = (const float*)d_in[2];
    const float* eb1  = (const float*)d_in[3];
    const float* eg1  = (const float*)d_in[4];
    const float* ebe1 = (const float*)d_in[5];
    const float* ew2  = (const float*)d_in[6];
    const float* eb2  = (const float*)d_in[7];
    const float* eg2  = (const float*)d_in[8];
    const float* ebe2 = (const float*)d_in[9];
    const float* vw0  = (const float*)d_in[10];
    const float* vb0  = (const float*)d_in[11];
    const float* vg0  = (const float*)d_in[12];
    const float* vbe0 = (const float*)d_in[13];
    const float* vw1  = (const float*)d_in[14];
    const float* vb1  = (const float*)d_in[15];
    const float* vg1  = (const float*)d_in[16];
    const float* vbe1 = (const float*)d_in[17];
    const float* vw2  = (const float*)d_in[18];
    const float* vb2  = (const float*)d_in[19];
    const float* vg2  = (const float*)d_in[20];
    const float* vbe2 = (const float*)d_in[21];
    const float* vw3  = (const float*)d_in[22];
    const float* vb3  = (const float*)d_in[23];
    const float* wv   = (const float*)d_in[24];
    const float* bv   = (const float*)d_in[25];
    const float* wo   = (const float*)d_in[26];
    const float* bo   = (const float*)d_in[27];
    const float* dw1  = (const float*)d_in[28];
    const float* db1  = (const float*)d_in[29];
    const float* dw2  = (const float*)d_in[30];
    const float* db2  = (const float*)d_in[31];
    const float* dw3  = (const float*)d_in[32];
    const float* db3  = (const float*)d_in[33];

    char* ws = (char*)d_ws;
    size_t off = 0;
    auto take = [&](size_t bytes) { char* p = ws + off; off += (bytes + 255) & ~(size_t)255; return p; };
    uint32_t* Ach0  = (uint32_t*)take((size_t)CH * B * ADW * 4);    // 64 MiB
    uint32_t* Ach1  = (uint32_t*)take((size_t)CH * B * ADW * 4);    // 64 MiB
    uint32_t* dxp   = (uint32_t*)take((size_t)NSTEP * B * 32 * 4);  // 1 MiB (padded rows)
    float*    bd3g  = (float*)take((size_t)NSTEP * B * H * 4);      // 4 MiB
    float*    dtb   = (float*)take(NSTEP * 4);
    float*    zbuf  = (float*)take((size_t)B * H * 4);
    float*    att   = (float*)take((size_t)B * H * 4);
    uint32_t* wcol  = (uint32_t*)take((size_t)160 * 512 * 4);       // 320 KB
    uint32_t* wp    = (uint32_t*)take((size_t)32768 * 32 * 4);      // 4 MiB
    uint32_t* AchB[2] = { Ach0, Ach1 };

    pack_kernel<<<(32768 * 32 + 255) / 256, 256, 0, stream>>>(vw0, vw1, vw2, vw3, wcol, wp);
    prep_kernel<<<B, 128, 0, stream>>>(path, ts, ew1, eb1, eg1, ebe1,
                                       ew2, eb2, eg2, ebe2, vb3, zbuf, dxp, bd3g, dtb);
    // chunk 0's A has nothing to hide under
    amm_kernel<<<1024, 256, 0, stream>>>(wp, dxp, AchB[0], 0);
    for (int c = 0; c < NCH; ++c) {
        int grid = (c < NCH - 1) ? (B + 512) : B;   // last chunk: scan only
        int s_amm = (c < NCH - 1) ? (c + 1) * CH : 0;   // unused when grid==B
        fused_kernel<<<grid, 512, 0, stream>>>(
            wcol, AchB[c & 1], AchB[(c + 1) & 1], wp, dxp,
            vb0, vg0, vbe0, vb1, vg1, vbe1, vb2, vg2, vbe2,
            bd3g, dtb, zbuf, c * CH, s_amm);
    }
    att_kernel<<<B, 128, 0, stream>>>(zbuf, wv, bv, wo, bo, att);
    dec_kernel<<<T * B, 64, 0, stream>>>(att, dw1, db1, dw2, db2, dw3, db3, (float*)d_out);
}

// Round 9
// 550.591 us; speedup vs baseline: 1.1452x; 1.1452x over previous
//
#include <hip/hip_runtime.h>
#include <cstdint>

constexpr int B    = 256;
constexpr int S    = 33;
constexpr int D    = 42;
constexpr int H    = 128;
constexpr int HFF  = 256;
constexpr int T    = 20;
constexpr int NSTEP = S - 1;   // 32
constexpr int DP   = D / 2;    // 21 f16 d-pairs
constexpr int ADW  = 8192;     // dwords per (s,b) A-slice (e5m2, 32 KB)
constexpr int CH   = 16;       // steps per chunk (A chunk = 128 MiB)
constexpr int NCH  = NSTEP / CH;  // 2 chunks
#define BN_SCALE 0.9999950000374997f

typedef _Float16 h2v __attribute__((ext_vector_type(2)));
typedef _Float16 f16x8 __attribute__((ext_vector_type(8)));
typedef float    f32x4 __attribute__((ext_vector_type(4)));
union UH2 { uint32_t u; h2v h; };

__device__ __forceinline__ float fdot2u(uint32_t a, uint32_t b, float c) {
    UH2 x, y; x.u = a; y.u = b;
    return __builtin_amdgcn_fdot2(x.h, y.h, c, false);
}
__device__ __forceinline__ uint32_t packh2(float a, float b) {
    UH2 u; u.h = h2v{(_Float16)a, (_Float16)b}; return u.u;
}
__device__ __forceinline__ float gelu_exact(float x) {
    return 0.5f * x * (1.0f + erff(x * 0.70710678118654752f));
}
// fast gelu for the hot scan (err ~3e-4, far under the 1e-2 threshold)
__device__ __forceinline__ float gelu_fast(float x) {
    float inner = x * (1.0f + 0.044715f * x * x);
    float E = __expf(1.5957691216f * inner);
    return x * E * __frcp_rn(E + 1.0f);
}
// A-staging swizzle (uint4 index): column ^= (row>>4)<<1 so that L3's
// intra-wave (h = t>>2, g = t&3) reads land 2-way max on LDS banks.
__device__ __forceinline__ int aswz(int idx) {
    return (idx & ~31) | ((idx & 31) ^ (((idx >> 9) & 3) << 1));
}

// ---------------------------------------------------------------------------
// Pack (one-time):
//  wcol[r*512 + t]: f16-pair weight-column slices for the 512-thread scan.
//  wp[m][64] f16 (32 dwords/row): A-operand for the MFMA aphase.
//    m = byte index in an A-slice: e = 4*(m>>9) + (m&3); h = (m>>2)&127;
//    wp[m][d] = w3[e][h*D + d] for d<42, else 0.  Positional (identity-d)
//    packing of BOTH operands makes the intra-fragment k order cancel.
// ---------------------------------------------------------------------------
__global__ void pack_kernel(const float* __restrict__ w0, const float* __restrict__ w1,
                            const float* __restrict__ w2, const float* __restrict__ w3,
                            uint32_t* __restrict__ wcol, uint32_t* __restrict__ wp) {
    int idx = blockIdx.x * 256 + threadIdx.x;
    if (idx < 160 * 512) {
        int r = idx >> 9, t = idx & 511;
        int j = t >> 1, half = t & 1;
        float a, bb;
        if (r < 32)      { int ip = half * 32 + r;      a = w0[(2*ip)*HFF + j]; bb = w0[(2*ip+1)*HFF + j]; }
        else if (r < 96) { int ip = half * 64 + (r-32); a = w1[(2*ip)*HFF + j]; bb = w1[(2*ip+1)*HFF + j]; }
        else             { int ip = half * 64 + (r-96); a = w2[(2*ip)*HFF + j]; bb = w2[(2*ip+1)*HFF + j]; }
        wcol[idx] = packh2(a, bb);
    }
    if (idx < 32768 * 32) {
        int m = idx >> 5, dd = (idx & 31) * 2;
        int e = 4 * (m >> 9) + (m & 3);
        int h = (m >> 2) & 127;
        const float* row = w3 + (size_t)e * (H * D) + h * D;
        float a = (dd     < D) ? row[dd]     : 0.f;
        float b = (dd + 1 < D) ? row[dd + 1] : 0.f;
        wp[idx] = packh2(a, b);
    }
}

// ---------------------------------------------------------------------------
// Prep: encoder z0, dxdt padded f16 rows (64 wide, zeros d>=42), bd3g, dt.
// ---------------------------------------------------------------------------
__global__ void prep_kernel(const float* __restrict__ path, const float* __restrict__ ts,
                            const float* __restrict__ ew1, const float* __restrict__ eb1,
                            const float* __restrict__ eg1, const float* __restrict__ ebe1,
                            const float* __restrict__ ew2, const float* __restrict__ eb2,
                            const float* __restrict__ eg2, const float* __restrict__ ebe2,
                            const float* __restrict__ b3,
                            float* __restrict__ zbuf, uint32_t* __restrict__ dxp,
                            float* __restrict__ bd3g, float* __restrict__ dtb) {
    __shared__ float x0[D], hb[H], dxs[NSTEP][D];
    int b = blockIdx.x, tid = threadIdx.x;
    if (tid < D) x0[tid] = path[b * S * D + tid];
    __syncthreads();
    {
        float acc = eb1[tid];
        for (int d = 0; d < D; ++d) acc += x0[d] * ew1[d * H + tid];
        hb[tid] = gelu_exact(acc * (eg1[tid] * BN_SCALE) + ebe1[tid]);
    }
    __syncthreads();
    {
        float acc = eb2[tid];
        for (int i = 0; i < H; ++i) acc += hb[i] * ew2[i * H + tid];
        zbuf[b * H + tid] = acc * (eg2[tid] * BN_SCALE) + ebe2[tid];
    }
    for (int idx = tid; idx < NSTEP * 32; idx += 128) {
        int s = idx >> 5, j2 = idx & 31;
        uint32_t val = 0;
        if (j2 < DP) {
            float dtv = ts[s + 1] - ts[s];
            int base = b * S * D + s * D + 2 * j2;
            float v0 = (path[base + D] - path[base]) / dtv;
            float v1 = (path[base + D + 1] - path[base + 1]) / dtv;
            dxs[s][2 * j2] = v0; dxs[s][2 * j2 + 1] = v1;
            val = packh2(v0, v1);
        }
        dxp[((size_t)(s * B + b)) * 32 + j2] = val;
    }
    __syncthreads();
    for (int s = 0; s < NSTEP; ++s) {
        float a = 0.f;
        for (int d = 0; d < D; ++d) a += b3[tid * D + d] * dxs[s][d];
        bd3g[(size_t)(s * B + b) * H + tid] = a;
    }
    if (b == 0 && tid < NSTEP) dtb[tid] = ts[tid + 1] - ts[tid];
}

// ---------------------------------------------------------------------------
// MFMA A-phase v2: identical HBM layout to round 7 (scan untouched), but
// stores coalesced via a per-wave LDS transpose.  Round-8 data showed the
// old per-dword scatter (4-B stores at 32-KB lane stride = 16 quarter-line
// transactions per store, ~65K line-transactions/CU) made amm ~90 us/chunk
// (VMEM-transaction-bound, MfmaUtil 2.7%).  Here each wave writes its 8
// packed dwords per (q-row) into LDS [16 q][36 dwords] (slot = lk+4*mi =
// output dword idx; stride 36 -> 2-way-free writes, 16-B-aligned b128
// reads), then lanes re-read consecutive output dwords and issue 2 uint4
// stores: 16 q-segments x 64 B fully dense lines, 8x fewer store instrs.
// grid = 64 mg-groups x 32 slice-groups = 2048 blocks, 256 thr = 4 waves.
// ---------------------------------------------------------------------------
__global__ void __launch_bounds__(256) amm_kernel(
    const uint32_t* __restrict__ wp, const uint32_t* __restrict__ dxp,
    uint32_t* __restrict__ Ach, int s0) {
    __shared__ __align__(16) uint32_t xpose[4][16 * 36];   // 9.2 KB
    int t = threadIdx.x;
    int l = t & 63, wid = t >> 6;
    int mg = (blockIdx.x & 63) * 4 + wid;        // 0..255
    int sg = blockIdx.x >> 6;                    // 0..31
    int lr = l & 15, lk = l >> 4;
    const char* wpB = (const char*)wp;
    const char* dxB = (const char*)dxp + (size_t)s0 * B * 128;
    char* asB = (char*)Ach;
    uint32_t* xp = xpose[wid];
    f16x8 af0[8], af1[8];
#pragma unroll
    for (int mi = 0; mi < 8; ++mi) {
        const f16x8* p = (const f16x8*)(wpB + ((size_t)(mg * 8 + mi) * 16 + lr) * 128 + lk * 16);
        af0[mi] = p[0]; af1[mi] = p[4];          // d 0..31, d 32..63
    }
#pragma unroll
    for (int si = 0; si < 8; ++si) {
        int q = sg * 128 + si * 16 + lr;         // chunk-local slice (this lane's C col)
#pragma unroll
        for (int mi = 0; mi < 8; ++mi) {
            const f16x8* bp = (const f16x8*)(dxB + (size_t)q * 128 + lk * 16);
            f16x8 b0 = bp[0], b1 = bp[4];
            f32x4 acc = {0.f, 0.f, 0.f, 0.f};
            acc = __builtin_amdgcn_mfma_f32_16x16x32_f16(af0[mi], b0, acc, 0, 0, 0);
            acc = __builtin_amdgcn_mfma_f32_16x16x32_f16(af1[mi], b1, acc, 0, 0, 0);
            // C rows (lane>>4)*4+reg = 4 consecutive m bytes -> 1 dword
            uint32_t P0 = packh2(acc[0], acc[1]) + 0x00800080u;
            uint32_t P1 = packh2(acc[2], acc[3]) + 0x00800080u;
            uint32_t Q = __builtin_amdgcn_perm(P1, P0, 0x07050301u);
            // output dword idx within this q's 128-B mg group = lk + 4*mi
            xp[lr * 36 + lk + 4 * mi] = Q;
        }
        __syncthreads();
        // coalesced write-out: lane covers (q_row = l>>2, output dwords (l&3)*8..+7)
        {
            int qr = l >> 2, seg = l & 3;
            const uint4* src = (const uint4*)(xp + qr * 36 + seg * 8);
            uint4 v0 = src[0], v1 = src[1];
            int qout = sg * 128 + si * 16 + qr;
            char* outB = asB + (size_t)qout * 32768 + mg * 128 + seg * 32;
            *(uint4*)outB = v0;
            *(uint4*)(outB + 16) = v1;
        }
        __syncthreads();
    }
}

// ---------------------------------------------------------------------------
// Scan (per 16-step chunk): round-4/7 structure verbatim (proven 158 us,
// VGPR 120, no spill): 512 thr, 4 fused phases/stage, 4-acc ILP, fused
// L3+state via (h = t>>2, g = t&3) lane map, aswz A-swizzle.
// ---------------------------------------------------------------------------
__global__ void __launch_bounds__(512, 1)
__attribute__((amdgpu_waves_per_eu(2, 8)))
scan_kernel(
    const uint32_t* __restrict__ wcol, const uint32_t* __restrict__ Ach,
    const float* __restrict__ vb0, const float* __restrict__ vg0, const float* __restrict__ vbe0,
    const float* __restrict__ vb1, const float* __restrict__ vg1, const float* __restrict__ vbe1,
    const float* __restrict__ vb2, const float* __restrict__ vg2, const float* __restrict__ vbe2,
    const float* __restrict__ bd3g, const float* __restrict__ dtb,
    float* __restrict__ zbuf, int s0) {
    __shared__ __align__(16) uint32_t ABUF[2][ADW];            // 64 KB
    __shared__ __align__(16) uint32_t zzPd[72];                // half*36 + r
    __shared__ __align__(16) uint32_t yA[136], yB[136], yC[136]; // half*68 + r
    int t = threadIdx.x, b = blockIdx.x;
    int j = t >> 1, half = t & 1;                     // MLP role
    int h = t >> 2, g = t & 3;                        // L3/state role
    int hswz = h ^ (g << 3);                          // swizzled A column
    uint32_t w0h[32], w1h[64], w2h[64];
#pragma unroll
    for (int r = 0; r < 32; ++r) w0h[r] = wcol[r * 512 + t];
#pragma unroll
    for (int r = 0; r < 64; ++r) w1h[r] = wcol[(32 + r) * 512 + t];
#pragma unroll
    for (int r = 0; r < 64; ++r) w2h[r] = wcol[(96 + r) * 512 + t];
    // folded BN: out = gelu(p*cs + co)
    float c0s = vg0[j] * BN_SCALE, c0o = vb0[j] * c0s + vbe0[j];
    float c1s = vg1[j] * BN_SCALE, c1o = vb1[j] * c1s + vbe1[j];
    float c2s = vg2[j] * BN_SCALE, c2o = vb2[j] * c2s + vbe2[j];
    float zf = zbuf[b * H + h];
    // prologue: stage A for local step 0 (swizzled)
    {
        const uint4* Ag = (const uint4*)(Ach + (size_t)b * ADW);
        uint4 a0 = Ag[t], a1 = Ag[512 + t], a2 = Ag[1024 + t], a3 = Ag[1536 + t];
        uint4* Ad = (uint4*)ABUF[0];
        Ad[aswz(t)] = a0; Ad[aswz(512 + t)] = a1;
        Ad[aswz(1024 + t)] = a2; Ad[aswz(1536 + t)] = a3;
    }
    {
        float zhi = __shfl_down(zf, 4, 64);
        if ((t & 7) == 0) {
            int ip = t >> 3;
            zzPd[(ip >> 5) * 36 + (ip & 31)] = packh2(zf, zhi);
        }
    }
    __syncthreads();

    for (int sl = 0; sl < CH; ++sl) {
        int s = s0 + sl;
        float hstep = dtb[s];
        float bd3 = bd3g[(size_t)(s * B + b) * H + h];
        // prefetch next step's A into registers (in flight across the step)
        uint4 pf0, pf1, pf2, pf3;
        {
            int sn = (sl + 1 < CH) ? sl + 1 : sl;
            const uint4* Ag = (const uint4*)(Ach + (size_t)(sn * B + b) * ADW);
            pf0 = Ag[t]; pf1 = Ag[512 + t]; pf2 = Ag[1024 + t]; pf3 = Ag[1536 + t];
        }
        const uint32_t* AL = ABUF[sl & 1];
        float ksum = 0.f, kcur = 0.f;
        for (int r = 0; r < 4; ++r) {
            // ---- L0: 128 -> 256 (half-K per lane, 4 accumulators) ----
            {
                float pa = 0.f, pb = 0.f, pc = 0.f, pd = 0.f;
                const uint4* zq = (const uint4*)(zzPd + half * 36);
#pragma unroll
                for (int u4 = 0; u4 < 8; ++u4) {
                    uint4 zv = zq[u4];
                    pa = fdot2u(w0h[4*u4+0], zv.x, pa); pb = fdot2u(w0h[4*u4+1], zv.y, pb);
                    pc = fdot2u(w0h[4*u4+2], zv.z, pc); pd = fdot2u(w0h[4*u4+3], zv.w, pd);
                }
                float p = (pa + pb) + (pc + pd);
                p += __shfl_xor(p, 1, 64);
                float v = gelu_fast(p * c0s + c0o);
                float vhi = __shfl_down(v, 2, 64);
                if ((t & 3) == 0) {
                    int ip = t >> 2;
                    yA[(ip >> 6) * 68 + (ip & 63)] = packh2(v, vhi);
                }
            }
            __syncthreads();
            // ---- L1: 256 -> 256 (4 accumulators) ----
            {
                float pa = 0.f, pb = 0.f, pc = 0.f, pd = 0.f;
                const uint4* yq = (const uint4*)(yA + half * 68);
#pragma unroll
                for (int u4 = 0; u4 < 16; ++u4) {
                    uint4 yv = yq[u4];
                    pa = fdot2u(w1h[4*u4+0], yv.x, pa); pb = fdot2u(w1h[4*u4+1], yv.y, pb);
                    pc = fdot2u(w1h[4*u4+2], yv.z, pc); pd = fdot2u(w1h[4*u4+3], yv.w, pd);
                }
                float p = (pa + pb) + (pc + pd);
                p += __shfl_xor(p, 1, 64);
                float v = gelu_fast(p * c1s + c1o);
                float vhi = __shfl_down(v, 2, 64);
                if ((t & 3) == 0) {
                    int ip = t >> 2;
                    yB[(ip >> 6) * 68 + (ip & 63)] = packh2(v, vhi);
                }
            }
            __syncthreads();
            // ---- L2: 256 -> 256 (4 accumulators) ----
            {
                float pa = 0.f, pb = 0.f, pc = 0.f, pd = 0.f;
                const uint4* yq = (const uint4*)(yB + half * 68);
#pragma unroll
                for (int u4 = 0; u4 < 16; ++u4) {
                    uint4 yv = yq[u4];
                    pa = fdot2u(w2h[4*u4+0], yv.x, pa); pb = fdot2u(w2h[4*u4+1], yv.y, pb);
                    pc = fdot2u(w2h[4*u4+2], yv.z, pc); pd = fdot2u(w2h[4*u4+3], yv.w, pd);
                }
                float p = (pa + pb) + (pc + pd);
                p += __shfl_xor(p, 1, 64);
                float v = gelu_fast(p * c2s + c2o);
                float vhi = __shfl_down(v, 2, 64);
                if ((t & 3) == 0) {
                    int ip = t >> 2;
                    yC[(ip >> 6) * 68 + (ip & 63)] = packh2(v, vhi);
                }
            }
            __syncthreads();
            // ---- L3 + state (fused): lane (h = t>>2, g = t&3) covers
            //      k-quads g*16..g*16+15; intra-wave reduce over g. ----
            {
                float pA = 0.f, pB = 0.f, pC = 0.f, pD = 0.f;
                int ybase = (g >> 1) * 68 + (g & 1) * 32;
                const uint4* yq = (const uint4*)(yC + ybase);
#pragma unroll
                for (int kk = 0; kk < 8; ++kk) {
                    uint4 yv = yq[kk];
                    int k0 = g * 16 + 2 * kk;
                    uint32_t Qa = AL[k0 * 128 + hswz];
                    uint32_t Qb = AL[(k0 + 1) * 128 + hswz];
                    pA = fdot2u(__builtin_amdgcn_perm(0u, Qa, 0x010C000Cu), yv.x, pA);
                    pB = fdot2u(__builtin_amdgcn_perm(0u, Qa, 0x030C020Cu), yv.y, pB);
                    pC = fdot2u(__builtin_amdgcn_perm(0u, Qb, 0x010C000Cu), yv.z, pC);
                    pD = fdot2u(__builtin_amdgcn_perm(0u, Qb, 0x030C020Cu), yv.w, pD);
                }
                float ptot = (pA + pB) + (pC + pD);
                ptot += __shfl_xor(ptot, 1, 64);
                ptot += __shfl_xor(ptot, 2, 64);
                kcur = bd3 + ptot;                    // redundant across g-lanes
                float wsm = (r == 1 || r == 2) ? 2.f : 1.f;
                ksum += wsm * kcur;
                float zz;
                if (r < 3) {
                    float cin = (r == 2) ? 1.f : 0.5f;
                    zz = zf + cin * hstep * kcur;
                } else {
                    zf += hstep * (1.f / 6.f) * ksum;
                    zz = zf;
                }
                float zhi = __shfl_down(zz, 4, 64);
                if ((t & 7) == 0) {
                    int ip = t >> 3;
                    zzPd[(ip >> 5) * 36 + (ip & 31)] = packh2(zz, zhi);
                }
            }
            if (r == 3) {  // stage prefetched A into the other buffer (swizzled)
                uint4* Ad = (uint4*)ABUF[(sl + 1) & 1];
                Ad[aswz(t)] = pf0; Ad[aswz(512 + t)] = pf1;
                Ad[aswz(1024 + t)] = pf2; Ad[aswz(1536 + t)] = pf3;
            }
            __syncthreads();
        }
    }
    if ((t & 3) == 0) zbuf[b * H + h] = zf;
}

// ---------------------------------------------------------------------------
// attended = (zT@wv+bv)@wo+bo.  One block per sample, 128 threads.
// ---------------------------------------------------------------------------
__global__ void att_kernel(const float* __restrict__ zbuf,
                           const float* __restrict__ wv, const float* __restrict__ bv,
                           const float* __restrict__ wo, const float* __restrict__ bo,
                           float* __restrict__ att) {
    __shared__ float zl[H], v[H];
    int b = blockIdx.x, tid = threadIdx.x;
    zl[tid] = zbuf[b * H + tid];
    __syncthreads();
    {
        float acc = bv[tid];
#pragma unroll 8
        for (int i = 0; i < H; ++i) acc += zl[i] * wv[i * H + tid];
        v[tid] = acc;
    }
    __syncthreads();
    {
        float acc = bo[tid];
#pragma unroll 8
        for (int i = 0; i < H; ++i) acc += v[i] * wo[i * H + tid];
        att[b * H + tid] = acc;
    }
}

// ---------------------------------------------------------------------------
// Decoder: one single-wave block per (t, b).  grid = T*B = 5120.
// ---------------------------------------------------------------------------
__global__ void __launch_bounds__(64) dec_kernel(
    const float* __restrict__ att,
    const float* __restrict__ dw1, const float* __restrict__ db1,
    const float* __restrict__ dw2, const float* __restrict__ db2,
    const float* __restrict__ dw3, const float* __restrict__ db3,
    float* __restrict__ out) {
    int bid = blockIdx.x;
    int t = bid >> 8, b = bid & 255;
    int tid = threadIdx.x;
    __shared__ float al[H], h1l[64];
    al[tid] = att[b * H + tid];
    al[tid + 64] = att[b * H + tid + 64];
    __syncthreads();
    {
        float acc = db1[t * 64 + tid];
#pragma unroll 8
        for (int i = 0; i < H; ++i) acc += al[i] * dw1[t * H * 64 + i * 64 + tid];
        h1l[tid] = gelu_exact(acc);
    }
    __syncthreads();
    float v = 0.f;
    if (tid < 32) {
        float acc = db2[t * 32 + tid];
#pragma unroll 8
        for (int i = 0; i < 64; ++i) acc += h1l[i] * dw2[t * 64 * 32 + i * 32 + tid];
        v = gelu_exact(acc) * dw3[t * 32 + tid];
    }
#pragma unroll
    for (int off = 16; off >= 1; off >>= 1) v += __shfl_down(v, off, 64);
    if (tid == 0) out[b * T + t] = 1.f / (1.f + expf(-(v + db3[t])));
}

// ---------------------------------------------------------------------------
extern "C" void kernel_launch(void* const* d_in, const int* in_sizes, int n_in,
                              void* d_out, int out_size, void* d_ws, size_t ws_size,
                              hipStream_t stream) {
    const float* path = (const float*)d_in[0];
    const float* ts   = (const float*)d_in[1];
    const float* ew1  = (const float*)d_in[2];
    const float* eb1  = (const float*)d_in[3];
    const float* eg1  = (const float*)d_in[4];
    const float* ebe1 = (const float*)d_in[5];
    const float* ew2  = (const float*)d_in[6];
    const float* eb2  = (const float*)d_in[7];
    const float* eg2  = (const float*)d_in[8];
    const float* ebe2 = (const float*)d_in[9];
    const float* vw0  = (const float*)d_in[10];
    const float* vb0  = (const float*)d_in[11];
    const float* vg0  = (const float*)d_in[12];
    const float* vbe0 = (const float*)d_in[13];
    const float* vw1  = (const float*)d_in[14];
    const float* vb1  = (const float*)d_in[15];
    const float* vg1  = (const float*)d_in[16];
    const float* vbe1 = (const float*)d_in[17];
    const float* vw2  = (const float*)d_in[18];
    const float* vb2  = (const float*)d_in[19];
    const float* vg2  = (const float*)d_in[20];
    const float* vbe2 = (const float*)d_in[21];
    const float* vw3  = (const float*)d_in[22];
    const float* vb3  = (const float*)d_in[23];
    const float* wv   = (const float*)d_in[24];
    const float* bv   = (const float*)d_in[25];
    const float* wo   = (const float*)d_in[26];
    const float* bo   = (const float*)d_in[27];
    const float* dw1  = (const float*)d_in[28];
    const float* db1  = (const float*)d_in[29];
    const float* dw2  = (const float*)d_in[30];
    const float* db2  = (const float*)d_in[31];
    const float* dw3  = (const float*)d_in[32];
    const float* db3  = (const float*)d_in[33];

    char* ws = (char*)d_ws;
    size_t off = 0;
    auto take = [&](size_t bytes) { char* p = ws + off; off += (bytes + 255) & ~(size_t)255; return p; };
    uint32_t* Ach   = (uint32_t*)take((size_t)CH * B * ADW * 4);    // 128 MiB
    uint32_t* dxp   = (uint32_t*)take((size_t)NSTEP * B * 32 * 4);  // 1 MiB (padded rows)
    float*    bd3g  = (float*)take((size_t)NSTEP * B * H * 4);      // 4 MiB
    float*    dtb   = (float*)take(NSTEP * 4);
    float*    zbuf  = (float*)take((size_t)B * H * 4);
    float*    att   = (float*)take((size_t)B * H * 4);
    uint32_t* wcol  = (uint32_t*)take((size_t)160 * 512 * 4);       // 320 KB
    uint32_t* wp    = (uint32_t*)take((size_t)32768 * 32 * 4);      // 4 MiB

    pack_kernel<<<(32768 * 32 + 255) / 256, 256, 0, stream>>>(vw0, vw1, vw2, vw3, wcol, wp);
    prep_kernel<<<B, 128, 0, stream>>>(path, ts, ew1, eb1, eg1, ebe1,
                                       ew2, eb2, eg2, ebe2, vb3, zbuf, dxp, bd3g, dtb);
    for (int c = 0; c < NCH; ++c) {
        amm_kernel<<<2048, 256, 0, stream>>>(wp, dxp, Ach, c * CH);
        scan_kernel<<<B, 512, 0, stream>>>(wcol, Ach,
                                           vb0, vg0, vbe0, vb1, vg1, vbe1, vb2, vg2, vbe2,
                                           bd3g, dtb, zbuf, c * CH);
    }
    att_kernel<<<B, 128, 0, stream>>>(zbuf, wv, bv, wo, bo, att);
    dec_kernel<<<T * B, 64, 0, stream>>>(att, dw1, db1, dw2, db2, dw3, db3, (float*)d_out);
}